// Round 5
// baseline (614.179 us; speedup 1.0000x reference)
//
#include <hip/hip_runtime.h>
#include <hip/hip_bf16.h>
#include <cstdint>
#include <cstddef>

// Problem constants (B=2, N=1024, C=512, H=8, hd=64, clusters=8)
#define NB   2
#define NN   1024
#define NC   512
#define NH   8
#define NHD  64
#define NK   8

typedef __attribute__((ext_vector_type(8))) short short8v;   // 8 bf16 (4 VGPRs)
typedef __attribute__((ext_vector_type(4))) short short4v;
typedef __attribute__((ext_vector_type(4))) float f32x4;

__device__ __forceinline__ short f2bf(float f) {
    union { float f; unsigned u; } v; v.f = f;
    unsigned r = v.u + 0x7FFFu + ((v.u >> 16) & 1u);   // RNE
    return (short)(r >> 16);
}
__device__ __forceinline__ float bf2f(short s) {
    union { unsigned u; float f; } v;
    v.u = ((unsigned)(unsigned short)s) << 16;
    return v.f;
}

// ---------------------------------------------------------------- cast f32->bf16
__global__ __launch_bounds__(256) void cast_kernel(
    const float* __restrict__ x, const float* __restrict__ wq,
    const float* __restrict__ wk, const float* __restrict__ wv,
    const float* __restrict__ wp,
    short* __restrict__ xb, short* __restrict__ wqb, short* __restrict__ wkb,
    short* __restrict__ wvb, short* __restrict__ wpb) {
    int i = blockIdx.x * 256 + threadIdx.x;
    if (i < NB * NN * NC) xb[i] = f2bf(x[i]);
    if (i < NC * NC) {
        wqb[i] = f2bf(wq[i]);
        wkb[i] = f2bf(wk[i]);
        wvb[i] = f2bf(wv[i]);
        wpb[i] = f2bf(wp[i]);
    }
}

// ---------------------------------------------------------------- QKV GEMM
// q/k: (2048,512) bf16.  v stored transposed per head: vT[b,h,d,i] bf16.
__global__ __launch_bounds__(256) void qkv_kernel(
    const short* __restrict__ xb, const short* __restrict__ wqb,
    const short* __restrict__ wkb, const short* __restrict__ wvb,
    short* __restrict__ qb, short* __restrict__ kb, short* __restrict__ vT) {
    __shared__ short As[64][40];
    __shared__ short Bs[64][40];
    const int tid = threadIdx.x;
    const int z = blockIdx.z;
    const short* Bsrc = (z == 0) ? wqb : ((z == 1) ? wkb : wvb);
    const int m0 = blockIdx.y * 64, n0 = blockIdx.x * 64;
    const int lane = tid & 63, wave = tid >> 6;
    const int wm = wave >> 1, wn = wave & 1, quad = lane >> 4, lr = lane & 15;
    const int row = tid >> 2, c0 = (tid & 3) * 8;
    f32x4 acc[2][2] = {};
    for (int kt = 0; kt < 512; kt += 32) {
        *(short8v*)&As[row][c0] = *(const short8v*)(xb + (m0 + row) * 512 + kt + c0);
        *(short8v*)&Bs[row][c0] = *(const short8v*)(Bsrc + (n0 + row) * 512 + kt + c0);
        __syncthreads();
        short8v a0 = *(short8v*)&As[wm * 32 + lr][quad * 8];
        short8v a1 = *(short8v*)&As[wm * 32 + 16 + lr][quad * 8];
        short8v b0 = *(short8v*)&Bs[wn * 32 + lr][quad * 8];
        short8v b1 = *(short8v*)&Bs[wn * 32 + 16 + lr][quad * 8];
        acc[0][0] = __builtin_amdgcn_mfma_f32_16x16x32_bf16(a0, b0, acc[0][0], 0, 0, 0);
        acc[0][1] = __builtin_amdgcn_mfma_f32_16x16x32_bf16(a0, b1, acc[0][1], 0, 0, 0);
        acc[1][0] = __builtin_amdgcn_mfma_f32_16x16x32_bf16(a1, b0, acc[1][0], 0, 0, 0);
        acc[1][1] = __builtin_amdgcn_mfma_f32_16x16x32_bf16(a1, b1, acc[1][1], 0, 0, 0);
        __syncthreads();
    }
    for (int sm = 0; sm < 2; sm++)
        for (int sn = 0; sn < 2; sn++)
            for (int r = 0; r < 4; r++) {
                int m = m0 + wm * 32 + sm * 16 + quad * 4 + r;
                int n = n0 + wn * 32 + sn * 16 + lr;
                short v = f2bf(acc[sm][sn][r]);
                if (z == 0) qb[m * 512 + n] = v;
                else if (z == 1) kb[m * 512 + n] = v;
                else {
                    int bb = m >> 10, i = m & 1023, h = n >> 6, d = n & 63;
                    vT[(size_t)(((bb * 8 + h) * 64 + d) << 10) + i] = v;
                }
            }
}

// ---------------------------------------------------------------- colsum of v per (b,h)
__global__ __launch_bounds__(256) void colsum_kernel(
    const short* __restrict__ vT, float* __restrict__ colsum) {
    __shared__ float cp[8][33];
    const int blk = blockIdx.x;     // bh*8 + dgroup
    const int bh = blk >> 3, dg = blk & 7;
    const int t = threadIdx.x;
    const int dl = t >> 5, seg = t & 31;
    const short* p = vT + (((size_t)(bh * 64 + dg * 8 + dl)) << 10) + seg * 32;
    float s = 0.f;
    for (int k = 0; k < 32; k += 8) {
        short8v v = *(const short8v*)(p + k);
        for (int j = 0; j < 8; j++) s += bf2f(v[j]);
    }
    cp[dl][seg] = s;
    __syncthreads();
    if (t < 8) {
        float v = 0.f;
        for (int s2 = 0; s2 < 32; s2++) v += cp[t][s2];
        colsum[bh * 64 + dg * 8 + t] = v;
    }
}

// ---------------------------------------------------------------- fused flash-style attention
// One block per (z, 64-row i-strip). Loops all 16 j-tiles:
//   s = scale*q k^T (MFMA) -> mask/exp epilogue writes ALL 8 cluster slices of
//   attn_map (NT stores, full-line coalesced) + e into LDS -> o += e @ v (MFMA).
// Row sums accumulate in registers; normalization + eps*colsum fused into the
// o epilogue. No eb scratch, no atomics, no separate zero/pv kernels.
__global__ __launch_bounds__(256) void attn_fused_kernel(
    const short* __restrict__ qb, const short* __restrict__ kb,
    const short* __restrict__ vT, const int* __restrict__ idx,
    const float* __restrict__ colsum, float* __restrict__ attn,
    short* __restrict__ oh) {
    __shared__ short Qs[64][72], Ks[64][72], Vs[64][72], Es[64][72];
    __shared__ float Ss[64][68];
    __shared__ int idxi[64], idxj[64];
    __shared__ float rowpart[64][17];
    __shared__ float invL[64], csL[64];
    const int tid = threadIdx.x;
    const int z = blockIdx.y, b = z >> 3, h = z & 7;
    const int i0 = blockIdx.x * 64;
    const int lane = tid & 63, wave = tid >> 6;
    const int wm = wave >> 1, wn = wave & 1, quad = lane >> 4, lr = lane & 15;
    const int r0 = tid >> 3, cc = (tid & 7) * 8;
    // Q strip (persistent) + idxi + csL
    *(short8v*)&Qs[r0][cc]      = *(const short8v*)(qb + (b * 1024 + i0 + r0) * 512 + h * 64 + cc);
    *(short8v*)&Qs[r0 + 32][cc] = *(const short8v*)(qb + (b * 1024 + i0 + r0 + 32) * 512 + h * 64 + cc);
    if (tid < 64) { idxi[tid] = idx[b * 1024 + i0 + tid]; csL[tid] = colsum[z * 64 + tid]; }
    f32x4 acc_o[2][2] = {};
    float rsum[4] = {0.f, 0.f, 0.f, 0.f};
    const int rL = tid >> 4, cI = tid & 15, cL = cI * 4;
    const f32x4 zero4 = {0.f, 0.f, 0.f, 0.f};
    for (int jt = 0; jt < 16; jt++) {
        const int j0 = jt * 64;
        *(short8v*)&Ks[r0][cc]      = *(const short8v*)(kb + (b * 1024 + j0 + r0) * 512 + h * 64 + cc);
        *(short8v*)&Ks[r0 + 32][cc] = *(const short8v*)(kb + (b * 1024 + j0 + r0 + 32) * 512 + h * 64 + cc);
        *(short8v*)&Vs[r0][cc]      = *(const short8v*)(vT + ((size_t)z << 16) + (r0 << 10) + j0 + cc);
        *(short8v*)&Vs[r0 + 32][cc] = *(const short8v*)(vT + ((size_t)z << 16) + ((r0 + 32) << 10) + j0 + cc);
        if (tid < 64) idxj[tid] = idx[b * 1024 + j0 + tid];
        __syncthreads();
        // s = q k^T
        f32x4 as[2][2] = {};
        for (int k0 = 0; k0 < 64; k0 += 32) {
            short8v a0 = *(short8v*)&Qs[wm * 32 + lr][k0 + quad * 8];
            short8v a1 = *(short8v*)&Qs[wm * 32 + 16 + lr][k0 + quad * 8];
            short8v b0 = *(short8v*)&Ks[wn * 32 + lr][k0 + quad * 8];
            short8v b1 = *(short8v*)&Ks[wn * 32 + 16 + lr][k0 + quad * 8];
            as[0][0] = __builtin_amdgcn_mfma_f32_16x16x32_bf16(a0, b0, as[0][0], 0, 0, 0);
            as[0][1] = __builtin_amdgcn_mfma_f32_16x16x32_bf16(a0, b1, as[0][1], 0, 0, 0);
            as[1][0] = __builtin_amdgcn_mfma_f32_16x16x32_bf16(a1, b0, as[1][0], 0, 0, 0);
            as[1][1] = __builtin_amdgcn_mfma_f32_16x16x32_bf16(a1, b1, as[1][1], 0, 0, 0);
        }
        for (int sm = 0; sm < 2; sm++)
            for (int sn = 0; sn < 2; sn++)
                for (int r = 0; r < 4; r++)
                    Ss[wm * 32 + sm * 16 + quad * 4 + r][wn * 32 + sn * 16 + lr] = as[sm][sn][r] * 0.125f;
        __syncthreads();
        // epilogue: mask, exp, write 8 slices + Es
        for (int ii = 0; ii < 4; ii++) {
            const int row = ii * 16 + rL;
            const int ci = idxi[row];
            f32x4 s4 = *(f32x4*)&Ss[row][cL];
            f32x4 m4;
            short4v e4;
            for (int kk = 0; kk < 4; kk++) {
                const bool in = (idxj[cL + kk] == ci);
                const float sv = s4[kk];
                m4[kk] = in ? sv : 0.f;
                const float ev = (in && sv != 0.f) ? __expf(sv) : 0.f;
                rsum[ii] += ev;
                e4[kk] = f2bf(ev);
            }
            float* base = attn + (((size_t)(b * 64 + h)) << 20) + (((size_t)(i0 + row)) << 10) + j0 + cL;
            for (int c = 0; c < 8; c++) {
                f32x4 w = (c == ci) ? m4 : zero4;
                __builtin_nontemporal_store(w, (f32x4*)(base + ((size_t)c << 23)));
            }
            *(short4v*)&Es[row][cL] = e4;
        }
        __syncthreads();
        // o += e @ v
        for (int k0 = 0; k0 < 64; k0 += 32) {
            short8v a0 = *(short8v*)&Es[wm * 32 + lr][k0 + quad * 8];
            short8v a1 = *(short8v*)&Es[wm * 32 + 16 + lr][k0 + quad * 8];
            short8v b0 = *(short8v*)&Vs[wn * 32 + lr][k0 + quad * 8];
            short8v b1 = *(short8v*)&Vs[wn * 32 + 16 + lr][k0 + quad * 8];
            acc_o[0][0] = __builtin_amdgcn_mfma_f32_16x16x32_bf16(a0, b0, acc_o[0][0], 0, 0, 0);
            acc_o[0][1] = __builtin_amdgcn_mfma_f32_16x16x32_bf16(a0, b1, acc_o[0][1], 0, 0, 0);
            acc_o[1][0] = __builtin_amdgcn_mfma_f32_16x16x32_bf16(a1, b0, acc_o[1][0], 0, 0, 0);
            acc_o[1][1] = __builtin_amdgcn_mfma_f32_16x16x32_bf16(a1, b1, acc_o[1][1], 0, 0, 0);
        }
        __syncthreads();
    }
    // row sums -> invL
    for (int ii = 0; ii < 4; ii++) rowpart[ii * 16 + rL][cI] = rsum[ii];
    __syncthreads();
    if (tid < 64) {
        float v = 0.f;
        for (int s = 0; s < 16; s++) v += rowpart[tid][s];
        invL[tid] = 1.f / (v + 1e-6f);
    }
    __syncthreads();
    // o epilogue: normalize + eps*colsum, store bf16
    const float epsN = 1e-6f / 1024.f;
    for (int sm = 0; sm < 2; sm++)
        for (int sn = 0; sn < 2; sn++)
            for (int r = 0; r < 4; r++) {
                int iLoc = wm * 32 + sm * 16 + quad * 4 + r;
                int d = wn * 32 + sn * 16 + lr;
                float val = (acc_o[sm][sn][r] + epsN * csL[d]) * invL[iLoc];
                oh[((size_t)(b * 1024 + i0 + iLoc)) * 512 + h * 64 + d] = f2bf(val);
            }
}

// ---------------------------------------------------------------- proj GEMM + bias
__global__ __launch_bounds__(256) void proj_kernel(
    const short* __restrict__ oh, const short* __restrict__ wpb,
    const float* __restrict__ bias, float* __restrict__ out) {
    __shared__ short As[64][40];
    __shared__ short Bs[64][40];
    const int tid = threadIdx.x;
    const int m0 = blockIdx.y * 64, n0 = blockIdx.x * 64;
    const int lane = tid & 63, wave = tid >> 6;
    const int wm = wave >> 1, wn = wave & 1, quad = lane >> 4, lr = lane & 15;
    const int row = tid >> 2, c0 = (tid & 3) * 8;
    f32x4 acc[2][2] = {};
    for (int kt = 0; kt < 512; kt += 32) {
        *(short8v*)&As[row][c0] = *(const short8v*)(oh + (m0 + row) * 512 + kt + c0);
        *(short8v*)&Bs[row][c0] = *(const short8v*)(wpb + (n0 + row) * 512 + kt + c0);
        __syncthreads();
        short8v a0 = *(short8v*)&As[wm * 32 + lr][quad * 8];
        short8v a1 = *(short8v*)&As[wm * 32 + 16 + lr][quad * 8];
        short8v b0 = *(short8v*)&Bs[wn * 32 + lr][quad * 8];
        short8v b1 = *(short8v*)&Bs[wn * 32 + 16 + lr][quad * 8];
        acc[0][0] = __builtin_amdgcn_mfma_f32_16x16x32_bf16(a0, b0, acc[0][0], 0, 0, 0);
        acc[0][1] = __builtin_amdgcn_mfma_f32_16x16x32_bf16(a0, b1, acc[0][1], 0, 0, 0);
        acc[1][0] = __builtin_amdgcn_mfma_f32_16x16x32_bf16(a1, b0, acc[1][0], 0, 0, 0);
        acc[1][1] = __builtin_amdgcn_mfma_f32_16x16x32_bf16(a1, b1, acc[1][1], 0, 0, 0);
        __syncthreads();
    }
    for (int sm = 0; sm < 2; sm++)
        for (int sn = 0; sn < 2; sn++)
            for (int r = 0; r < 4; r++) {
                int m = m0 + wm * 32 + sm * 16 + quad * 4 + r;
                int n = n0 + wn * 32 + sn * 16 + lr;
                out[(size_t)m * 512 + n] = acc[sm][sn][r] + bias[n];
            }
}

// ---------------------------------------------------------------- launch
extern "C" void kernel_launch(void* const* d_in, const int* in_sizes, int n_in,
                              void* d_out, int out_size, void* d_ws, size_t ws_size,
                              hipStream_t stream) {
    const float* x     = (const float*)d_in[0];
    const int*   idx   = (const int*)d_in[2];
    const float* Wq    = (const float*)d_in[4];
    const float* Wk    = (const float*)d_in[5];
    const float* Wv    = (const float*)d_in[6];
    const float* Wp    = (const float*)d_in[7];
    const float* bproj = (const float*)d_in[8];

    float* out  = (float*)d_out;
    float* attn = out + (size_t)NB * NN * NC;   // attn_map region (B,K,H,N,N)

    char* ws = (char*)d_ws;
    short* xb  = (short*)(ws + 0);           // 2 MB
    short* wqb = (short*)(ws + 2097152);     // 512 KB
    short* wkb = (short*)(ws + 2621440);
    short* wvb = (short*)(ws + 3145728);
    short* wpb = (short*)(ws + 3670016);
    short* qb  = (short*)(ws + 4194304);     // 2 MB
    short* kb  = (short*)(ws + 6291456);     // 2 MB
    short* vT  = (short*)(ws + 8388608);     // 2 MB
    short* oh  = (short*)(ws + 10485760);    // 2 MB
    float* colsum = (float*)(ws + 12582912); // 4 KB (B*H*64)

    cast_kernel<<<4096, 256, 0, stream>>>(x, Wq, Wk, Wv, Wp, xb, wqb, wkb, wvb, wpb);
    qkv_kernel<<<dim3(8, 32, 3), 256, 0, stream>>>(xb, wqb, wkb, wvb, qb, kb, vT);
    colsum_kernel<<<128, 256, 0, stream>>>(vT, colsum);
    attn_fused_kernel<<<dim3(16, 16), 256, 0, stream>>>(qb, kb, vT, idx, colsum, attn, oh);
    proj_kernel<<<dim3(8, 32, 1), 256, 0, stream>>>(oh, wpb, bproj, out);
}